// Round 5
// baseline (550.980 us; speedup 1.0000x reference)
//
#include <hip/hip_runtime.h>

// LSTM B=32768, T=50, I=2, H=32. 4096 blocks x 64 threads (1 wave / 8 rows).
// Single-wave blocks: NO barriers in the recurrence.
// BISECT from R3(pass)/R4(fail): KEEP M=8 + bpermute redistribute;
// REVERT x-projection to exact fp32 C-init (R3 scheme, consts via LDS table)
// and activations to R3's per-set form (CL=30, 2 rcp/set).
// Recurrent GEMM: mfma_f32_16x16x32_bf16 split precision (hh*Wh+hl*Wh+hh*Wl),
// hpk rows 8-15 zero. C/D rows 0-7 live on quads 0-1 -> redistribute via
// 16 ds_bpermute(lane^32) + cndmask so all 64 lanes do 4 activation sets.
// Output head = 3 MFMAs vs replicated W_out B-frag on the same A-fragment.

#define TS 50
#define HSTR 36     // u32 stride of hpk rows (144 B): 16B-aligned
#define CL 30.0f    // exp2 arg clamp (R3 value; products <= ~1.2e27, safe)

typedef short short8 __attribute__((ext_vector_type(8)));
typedef float f32x4 __attribute__((ext_vector_type(4)));

__device__ __forceinline__ float fast_exp2(float x) {
    return __builtin_amdgcn_exp2f(x);
}
__device__ __forceinline__ float fast_rcp(float x) {
    return __builtin_amdgcn_rcpf(x);
}
// v ~= hi + lo (bf16 each, trunc). returns (lo<<16)|hi
__device__ __forceinline__ unsigned split_pack(float v) {
    unsigned u   = __float_as_uint(v);
    float    res = v - __uint_as_float(u & 0xffff0000u);
    return __builtin_amdgcn_perm(__float_as_uint(res), u, 0x07060302u);
}
// (a & 0xffff) | (b << 16)
__device__ __forceinline__ unsigned lo_pair(unsigned a, unsigned b) {
    return __builtin_amdgcn_perm(b, a, 0x05040100u);
}
// (a >> 16) | (b & 0xffff0000)
__device__ __forceinline__ unsigned hi_pair(unsigned a, unsigned b) {
    return __builtin_amdgcn_perm(b, a, 0x07060302u);
}

union U4S8 { uint4 v; short8 s; unsigned u[4]; };

__global__ __launch_bounds__(64, 3)
void lsnn_kernel(const float* __restrict__ x,
                 const float* __restrict__ W_ih,
                 const float* __restrict__ W_hh,
                 const float* __restrict__ b_ih,
                 const float* __restrict__ b_hh,
                 const float* __restrict__ W_out,
                 const float* __restrict__ b_out,
                 const float* __restrict__ h0,
                 const float* __restrict__ c0,
                 float* __restrict__ out)
{
    __shared__ __align__(16) float    x_lds[8 * 100];    // 3200 B
    __shared__ __align__(16) unsigned hpk[16 * HSTR];    // 2304 B (rows 8-15 = 0)
    __shared__ __align__(16) float    out_lds[8 * TS];   // 1600 B
    __shared__ __align__(16) float4   cw_lds[128];       // 2048 B: {wx0,wx1,bias,0}

    const int  lane = threadIdx.x;
    const int  u0   = lane & 15;
    const int  q    = lane >> 4;
    const long b0   = (long)blockIdx.x * 8;
    const bool lowq = (q < 2);
    const int  paddr = (lane ^ 32) << 2;   // bpermute byte index

    // ---- stage x: 800 contiguous floats ----
    {
        const float4* xs = (const float4*)(x + b0 * 100);
        float4* xd = (float4*)x_lds;
        for (int i = lane; i < 200; i += 64) xd[i] = xs[i];
    }
    // ---- init packed h: rows 0-7 from h0, rows 8-15 zero ----
    for (int i = lane; i < 512; i += 64) {
        int r = i >> 5, u = i & 31;
        hpk[r * HSTR + u] = (r < 8) ? split_pack(h0[b0 * 32 + i]) : 0u;
    }

    const float L2E = 1.4426950408889634f;
    const float SG  = 2.0f * L2E;

    // ---- W_hh B-tiles (8): gate = n>>1, unit-half = n&1 ----
    short8 Bh[8], Bl[8];
    #pragma unroll
    for (int n = 0; n < 8; ++n) {
        const float s = ((n >> 1) == 2) ? (2.0f * L2E) : -L2E;
        const int   g = n * 16 + u0;
        const float* wr = W_hh + g * 32 + q * 8;
        U4S8 uh, ul;
        #pragma unroll
        for (int p = 0; p < 4; ++p) {
            unsigned p0 = split_pack(wr[2*p]   * s);
            unsigned p1 = split_pack(wr[2*p+1] * s);
            uh.u[p] = lo_pair(p0, p1);
            ul.u[p] = hi_pair(p0, p1);
        }
        Bh[n] = uh.s;  Bl[n] = ul.s;
    }
    // ---- C-init constant table: {wx0, wx1, bias, 0} per (tile n, col u0) ----
    #pragma unroll
    for (int n = 0; n < 8; ++n) {
        const float s = ((n >> 1) == 2) ? (2.0f * L2E) : -L2E;
        const int   g = n * 16 + u0;
        if (q == 0) {
            float4 cw;
            cw.x = W_ih[g * 2 + 0] * s;
            cw.y = W_ih[g * 2 + 1] * s;
            cw.z = (b_ih[g] + b_hh[g]) * s;
            cw.w = 0.0f;
            cw_lds[n * 16 + u0] = cw;
        }
    }
    // ---- head B-frag: B[k][n] = w_out[k] replicated over n ----
    short8 Bwh, Bwl;
    {
        U4S8 uh, ul;
        #pragma unroll
        for (int p = 0; p < 4; ++p) {
            unsigned p0 = split_pack(W_out[q * 8 + 2*p]);
            unsigned p1 = split_pack(W_out[q * 8 + 2*p + 1]);
            uh.u[p] = lo_pair(p0, p1);
            ul.u[p] = hi_pair(p0, p1);
        }
        Bwh = uh.s;  Bwl = ul.s;
    }
    const float bout = b_out[0];

    // ---- set ownership: rows rowbase+r (r=0..3), unit uu ----
    const int rowbase = (q & 1) * 4;
    const int uu      = (q >> 1) * 16 + u0;
    float cst[4];
    #pragma unroll
    for (int r = 0; r < 4; ++r)
        cst[r] = c0[(b0 + rowbase + r) * 32 + uu];

    const f32x4 ZV = {0.f, 0.f, 0.f, 0.f};
    const int abase = u0 * HSTR + q * 8;

    __syncthreads();

    #pragma unroll 1
    for (int t = 0; t < TS; ++t) {
        // ---- A-fragment h_{t-1}: row u0, k = q*8..q*8+7 ----
        uint4 hq0 = *(const uint4*)&hpk[abase];
        uint4 hq1 = *(const uint4*)&hpk[abase + 4];
        U4S8 Ahh, Ahl;
        Ahh.u[0] = lo_pair(hq0.x, hq0.y); Ahh.u[1] = lo_pair(hq0.z, hq0.w);
        Ahh.u[2] = lo_pair(hq1.x, hq1.y); Ahh.u[3] = lo_pair(hq1.z, hq1.w);
        Ahl.u[0] = hi_pair(hq0.x, hq0.y); Ahl.u[1] = hi_pair(hq0.z, hq0.w);
        Ahl.u[2] = hi_pair(hq1.x, hq1.y); Ahl.u[3] = hi_pair(hq1.z, hq1.w);

        // ---- output head for h_{t-1} ----
        if (t > 0) {
            f32x4 aw = ZV;
            aw = __builtin_amdgcn_mfma_f32_16x16x32_bf16(Ahh.s, Bwh, aw, 0, 0, 0);
            aw = __builtin_amdgcn_mfma_f32_16x16x32_bf16(Ahl.s, Bwh, aw, 0, 0, 0);
            aw = __builtin_amdgcn_mfma_f32_16x16x32_bf16(Ahh.s, Bwl, aw, 0, 0, 0);
            if (u0 == 0 && lowq) {
                #pragma unroll
                for (int r = 0; r < 4; ++r)
                    out_lds[(q * 4 + r) * TS + (t - 1)] = aw[r] + bout;
            }
        }

        // ---- x values for C-init: row m = q*4+r (rows 8-15 -> garbage, unused) ----
        float xr0[4], xr1[4];
        #pragma unroll
        for (int r = 0; r < 4; ++r) {
            float2 xv = *(const float2*)&x_lds[(((q * 4 + r) & 7)) * 100 + 2 * t];
            xr0[r] = xv.x;  xr1[r] = xv.y;
        }

        // ---- gates: exact fp32 C-init + 3 split-h MFMAs per tile ----
        f32x4 acc[8];
        #pragma unroll
        for (int n = 0; n < 8; ++n) {
            float4 cw = cw_lds[n * 16 + u0];
            f32x4 ci;
            #pragma unroll
            for (int r = 0; r < 4; ++r)
                ci[r] = fmaf(cw.y, xr1[r], fmaf(cw.x, xr0[r], cw.z));
            acc[n] = __builtin_amdgcn_mfma_f32_16x16x32_bf16(Ahh.s, Bh[n], ci,     0, 0, 0);
            acc[n] = __builtin_amdgcn_mfma_f32_16x16x32_bf16(Ahl.s, Bh[n], acc[n], 0, 0, 0);
            acc[n] = __builtin_amdgcn_mfma_f32_16x16x32_bf16(Ahh.s, Bl[n], acc[n], 0, 0, 0);
        }

        // ---- redistribute: quads 2-3 take the unit-half-1 sets (lane^32) ----
        float z[4][4];
        #pragma unroll
        for (int g = 0; g < 4; ++g) {
            #pragma unroll
            for (int r = 0; r < 4; ++r) {
                int rec = __builtin_amdgcn_ds_bpermute(
                              paddr, __float_as_int(acc[2 * g + 1][r]));
                z[g][r] = lowq ? acc[2 * g][r] : __int_as_float(rec);
            }
        }

        // ---- activations: R3's exact per-set form (5 exp2 + 2 rcp each) ----
        #pragma unroll
        for (int r = 0; r < 4; ++r) {
            float zi = fminf(z[0][r], CL);
            float zf = fminf(z[1][r], CL);
            float zg = fminf(z[2][r], CL);
            float zo = fminf(z[3][r], CL);
            float Av = fast_exp2(zi);         // e^{-i}
            float Bv = fast_exp2(zg);         // e^{2g}
            float Ev = fast_exp2(zf);         // e^{-f}
            float Ap = 1.0f + Av, Bp = 1.0f + Bv, Ep = 1.0f + Ev;
            float P1 = Ap * Bp;
            float R  = fast_rcp(P1 * Ep);
            float ig = (Bv - 1.0f) * (Ep * R);   // sigmoid(i)*tanh(g)
            float fv = P1 * R;                   // sigmoid(f)
            float c  = fmaf(fv, cst[r], ig);
            cst[r] = c;
            float Cv = fast_exp2(zo);            // e^{-o}
            float Dv = fast_exp2(fminf(SG * c, CL));  // e^{2c}
            float R2 = fast_rcp((1.0f + Cv) * (1.0f + Dv));
            float h  = (Dv - 1.0f) * R2;         // sigmoid(o)*tanh(c)
            hpk[(rowbase + r) * HSTR + uu] = split_pack(h);
        }
    }

    // ---- final head for h_49 ----
    {
        uint4 hq0 = *(const uint4*)&hpk[abase];
        uint4 hq1 = *(const uint4*)&hpk[abase + 4];
        U4S8 Ahh, Ahl;
        Ahh.u[0] = lo_pair(hq0.x, hq0.y); Ahh.u[1] = lo_pair(hq0.z, hq0.w);
        Ahh.u[2] = lo_pair(hq1.x, hq1.y); Ahh.u[3] = lo_pair(hq1.z, hq1.w);
        Ahl.u[0] = hi_pair(hq0.x, hq0.y); Ahl.u[1] = hi_pair(hq0.z, hq0.w);
        Ahl.u[2] = hi_pair(hq1.x, hq1.y); Ahl.u[3] = hi_pair(hq1.z, hq1.w);
        f32x4 aw = {0.f, 0.f, 0.f, 0.f};
        aw = __builtin_amdgcn_mfma_f32_16x16x32_bf16(Ahh.s, Bwh, aw, 0, 0, 0);
        aw = __builtin_amdgcn_mfma_f32_16x16x32_bf16(Ahl.s, Bwh, aw, 0, 0, 0);
        aw = __builtin_amdgcn_mfma_f32_16x16x32_bf16(Ahh.s, Bwl, aw, 0, 0, 0);
        if (u0 == 0 && lowq) {
            #pragma unroll
            for (int r = 0; r < 4; ++r)
                out_lds[(q * 4 + r) * TS + 49] = aw[r] + bout;
        }
    }

    __syncthreads();
    // ---- coalesced flush: 400 contiguous floats ----
    {
        float4* od = (float4*)(out + b0 * 50);
        const float4* os = (const float4*)out_lds;
        for (int i = lane; i < 100; i += 64) od[i] = os[i];
    }
}

extern "C" void kernel_launch(void* const* d_in, const int* in_sizes, int n_in,
                              void* d_out, int out_size, void* d_ws, size_t ws_size,
                              hipStream_t stream) {
    const float* x     = (const float*)d_in[0];
    const float* W_ih  = (const float*)d_in[1];
    const float* W_hh  = (const float*)d_in[2];
    const float* b_ih  = (const float*)d_in[3];
    const float* b_hh  = (const float*)d_in[4];
    const float* W_out = (const float*)d_in[5];
    const float* b_out = (const float*)d_in[6];
    const float* h0    = (const float*)d_in[7];
    const float* c0    = (const float*)d_in[8];
    float* out = (float*)d_out;

    dim3 grid(32768 / 8), block(64);
    lsnn_kernel<<<grid, block, 0, stream>>>(x, W_ih, W_hh, b_ih, b_hh,
                                            W_out, b_out, h0, c0, out);
}

// Round 6
// 220.182 us; speedup vs baseline: 2.5024x; 2.5024x over previous
//
#include <hip/hip_runtime.h>

// LSTM B=32768, T=50, I=2, H=32. 4096 blocks x 64 threads (1 wave / 8 rows).
// Single-wave blocks: NO barriers in the recurrence. Identical to R5 (passed,
// absmax 2e-3) except __launch_bounds__(64,2): R5's (64,3) register cap made
// the allocator spill the loop-invariant B-fragments to scratch (FETCH_SIZE
// 12.7MB -> 1.08GB, VALUBusy 17%). 256-VGPR budget = no spill (R2 precedent).
// Recurrent GEMM: mfma_f32_16x16x32_bf16 split precision (hh*Wh+hl*Wh+hh*Wl),
// hpk rows 8-15 zero. C/D rows 0-7 live on quads 0-1 -> redistribute via
// 16 ds_bpermute(lane^32) + cndmask so all 64 lanes do 4 activation sets.
// Output head = 3 MFMAs vs replicated W_out B-frag on the same A-fragment.

#define TS 50
#define HSTR 36     // u32 stride of hpk rows (144 B): 16B-aligned
#define CL 30.0f    // exp2 arg clamp

typedef short short8 __attribute__((ext_vector_type(8)));
typedef float f32x4 __attribute__((ext_vector_type(4)));

__device__ __forceinline__ float fast_exp2(float x) {
    return __builtin_amdgcn_exp2f(x);
}
__device__ __forceinline__ float fast_rcp(float x) {
    return __builtin_amdgcn_rcpf(x);
}
// v ~= hi + lo (bf16 each, trunc). returns (lo<<16)|hi
__device__ __forceinline__ unsigned split_pack(float v) {
    unsigned u   = __float_as_uint(v);
    float    res = v - __uint_as_float(u & 0xffff0000u);
    return __builtin_amdgcn_perm(__float_as_uint(res), u, 0x07060302u);
}
// (a & 0xffff) | (b << 16)
__device__ __forceinline__ unsigned lo_pair(unsigned a, unsigned b) {
    return __builtin_amdgcn_perm(b, a, 0x05040100u);
}
// (a >> 16) | (b & 0xffff0000)
__device__ __forceinline__ unsigned hi_pair(unsigned a, unsigned b) {
    return __builtin_amdgcn_perm(b, a, 0x07060302u);
}

union U4S8 { uint4 v; short8 s; unsigned u[4]; };

__global__ __launch_bounds__(64, 2)
void lsnn_kernel(const float* __restrict__ x,
                 const float* __restrict__ W_ih,
                 const float* __restrict__ W_hh,
                 const float* __restrict__ b_ih,
                 const float* __restrict__ b_hh,
                 const float* __restrict__ W_out,
                 const float* __restrict__ b_out,
                 const float* __restrict__ h0,
                 const float* __restrict__ c0,
                 float* __restrict__ out)
{
    __shared__ __align__(16) float    x_lds[8 * 100];    // 3200 B
    __shared__ __align__(16) unsigned hpk[16 * HSTR];    // 2304 B (rows 8-15 = 0)
    __shared__ __align__(16) float    out_lds[8 * TS];   // 1600 B
    __shared__ __align__(16) float4   cw_lds[128];       // 2048 B: {wx0,wx1,bias,0}

    const int  lane = threadIdx.x;
    const int  u0   = lane & 15;
    const int  q    = lane >> 4;
    const long b0   = (long)blockIdx.x * 8;
    const bool lowq = (q < 2);
    const int  paddr = (lane ^ 32) << 2;   // bpermute byte index

    // ---- stage x: 800 contiguous floats ----
    {
        const float4* xs = (const float4*)(x + b0 * 100);
        float4* xd = (float4*)x_lds;
        for (int i = lane; i < 200; i += 64) xd[i] = xs[i];
    }
    // ---- init packed h: rows 0-7 from h0, rows 8-15 zero ----
    for (int i = lane; i < 512; i += 64) {
        int r = i >> 5, u = i & 31;
        hpk[r * HSTR + u] = (r < 8) ? split_pack(h0[b0 * 32 + i]) : 0u;
    }

    const float L2E = 1.4426950408889634f;
    const float SG  = 2.0f * L2E;

    // ---- W_hh B-tiles (8): gate = n>>1, unit-half = n&1 ----
    short8 Bh[8], Bl[8];
    #pragma unroll
    for (int n = 0; n < 8; ++n) {
        const float s = ((n >> 1) == 2) ? (2.0f * L2E) : -L2E;
        const int   g = n * 16 + u0;
        const float* wr = W_hh + g * 32 + q * 8;
        U4S8 uh, ul;
        #pragma unroll
        for (int p = 0; p < 4; ++p) {
            unsigned p0 = split_pack(wr[2*p]   * s);
            unsigned p1 = split_pack(wr[2*p+1] * s);
            uh.u[p] = lo_pair(p0, p1);
            ul.u[p] = hi_pair(p0, p1);
        }
        Bh[n] = uh.s;  Bl[n] = ul.s;
    }
    // ---- C-init constant table: {wx0, wx1, bias, 0} per (tile n, col u0) ----
    #pragma unroll
    for (int n = 0; n < 8; ++n) {
        const float s = ((n >> 1) == 2) ? (2.0f * L2E) : -L2E;
        const int   g = n * 16 + u0;
        if (q == 0) {
            float4 cw;
            cw.x = W_ih[g * 2 + 0] * s;
            cw.y = W_ih[g * 2 + 1] * s;
            cw.z = (b_ih[g] + b_hh[g]) * s;
            cw.w = 0.0f;
            cw_lds[n * 16 + u0] = cw;
        }
    }
    // ---- head B-frag: B[k][n] = w_out[k] replicated over n ----
    short8 Bwh, Bwl;
    {
        U4S8 uh, ul;
        #pragma unroll
        for (int p = 0; p < 4; ++p) {
            unsigned p0 = split_pack(W_out[q * 8 + 2*p]);
            unsigned p1 = split_pack(W_out[q * 8 + 2*p + 1]);
            uh.u[p] = lo_pair(p0, p1);
            ul.u[p] = hi_pair(p0, p1);
        }
        Bwh = uh.s;  Bwl = ul.s;
    }
    const float bout = b_out[0];

    // ---- set ownership: rows rowbase+r (r=0..3), unit uu ----
    const int rowbase = (q & 1) * 4;
    const int uu      = (q >> 1) * 16 + u0;
    float cst[4];
    #pragma unroll
    for (int r = 0; r < 4; ++r)
        cst[r] = c0[(b0 + rowbase + r) * 32 + uu];

    const f32x4 ZV = {0.f, 0.f, 0.f, 0.f};
    const int abase = u0 * HSTR + q * 8;

    __syncthreads();

    #pragma unroll 1
    for (int t = 0; t < TS; ++t) {
        // ---- A-fragment h_{t-1}: row u0, k = q*8..q*8+7 ----
        uint4 hq0 = *(const uint4*)&hpk[abase];
        uint4 hq1 = *(const uint4*)&hpk[abase + 4];
        U4S8 Ahh, Ahl;
        Ahh.u[0] = lo_pair(hq0.x, hq0.y); Ahh.u[1] = lo_pair(hq0.z, hq0.w);
        Ahh.u[2] = lo_pair(hq1.x, hq1.y); Ahh.u[3] = lo_pair(hq1.z, hq1.w);
        Ahl.u[0] = hi_pair(hq0.x, hq0.y); Ahl.u[1] = hi_pair(hq0.z, hq0.w);
        Ahl.u[2] = hi_pair(hq1.x, hq1.y); Ahl.u[3] = hi_pair(hq1.z, hq1.w);

        // ---- output head for h_{t-1} ----
        if (t > 0) {
            f32x4 aw = ZV;
            aw = __builtin_amdgcn_mfma_f32_16x16x32_bf16(Ahh.s, Bwh, aw, 0, 0, 0);
            aw = __builtin_amdgcn_mfma_f32_16x16x32_bf16(Ahl.s, Bwh, aw, 0, 0, 0);
            aw = __builtin_amdgcn_mfma_f32_16x16x32_bf16(Ahh.s, Bwl, aw, 0, 0, 0);
            if (u0 == 0 && lowq) {
                #pragma unroll
                for (int r = 0; r < 4; ++r)
                    out_lds[(q * 4 + r) * TS + (t - 1)] = aw[r] + bout;
            }
        }

        // ---- x values for C-init: row m = q*4+r (rows 8-15 -> garbage, unused) ----
        float xr0[4], xr1[4];
        #pragma unroll
        for (int r = 0; r < 4; ++r) {
            float2 xv = *(const float2*)&x_lds[(((q * 4 + r) & 7)) * 100 + 2 * t];
            xr0[r] = xv.x;  xr1[r] = xv.y;
        }

        // ---- gates: exact fp32 C-init + 3 split-h MFMAs per tile ----
        f32x4 acc[8];
        #pragma unroll
        for (int n = 0; n < 8; ++n) {
            float4 cw = cw_lds[n * 16 + u0];
            f32x4 ci;
            #pragma unroll
            for (int r = 0; r < 4; ++r)
                ci[r] = fmaf(cw.y, xr1[r], fmaf(cw.x, xr0[r], cw.z));
            acc[n] = __builtin_amdgcn_mfma_f32_16x16x32_bf16(Ahh.s, Bh[n], ci,     0, 0, 0);
            acc[n] = __builtin_amdgcn_mfma_f32_16x16x32_bf16(Ahl.s, Bh[n], acc[n], 0, 0, 0);
            acc[n] = __builtin_amdgcn_mfma_f32_16x16x32_bf16(Ahh.s, Bl[n], acc[n], 0, 0, 0);
        }

        // ---- redistribute: quads 2-3 take the unit-half-1 sets (lane^32) ----
        float z[4][4];
        #pragma unroll
        for (int g = 0; g < 4; ++g) {
            #pragma unroll
            for (int r = 0; r < 4; ++r) {
                int rec = __builtin_amdgcn_ds_bpermute(
                              paddr, __float_as_int(acc[2 * g + 1][r]));
                z[g][r] = lowq ? acc[2 * g][r] : __int_as_float(rec);
            }
        }

        // ---- activations: per-set form (5 exp2 + 2 rcp each) ----
        #pragma unroll
        for (int r = 0; r < 4; ++r) {
            float zi = fminf(z[0][r], CL);
            float zf = fminf(z[1][r], CL);
            float zg = fminf(z[2][r], CL);
            float zo = fminf(z[3][r], CL);
            float Av = fast_exp2(zi);         // e^{-i}
            float Bv = fast_exp2(zg);         // e^{2g}
            float Ev = fast_exp2(zf);         // e^{-f}
            float Ap = 1.0f + Av, Bp = 1.0f + Bv, Ep = 1.0f + Ev;
            float P1 = Ap * Bp;
            float R  = fast_rcp(P1 * Ep);
            float ig = (Bv - 1.0f) * (Ep * R);   // sigmoid(i)*tanh(g)
            float fv = P1 * R;                   // sigmoid(f)
            float c  = fmaf(fv, cst[r], ig);
            cst[r] = c;
            float Cv = fast_exp2(zo);            // e^{-o}
            float Dv = fast_exp2(fminf(SG * c, CL));  // e^{2c}
            float R2 = fast_rcp((1.0f + Cv) * (1.0f + Dv));
            float h  = (Dv - 1.0f) * R2;         // sigmoid(o)*tanh(c)
            hpk[(rowbase + r) * HSTR + uu] = split_pack(h);
        }
    }

    // ---- final head for h_49 ----
    {
        uint4 hq0 = *(const uint4*)&hpk[abase];
        uint4 hq1 = *(const uint4*)&hpk[abase + 4];
        U4S8 Ahh, Ahl;
        Ahh.u[0] = lo_pair(hq0.x, hq0.y); Ahh.u[1] = lo_pair(hq0.z, hq0.w);
        Ahh.u[2] = lo_pair(hq1.x, hq1.y); Ahh.u[3] = lo_pair(hq1.z, hq1.w);
        Ahl.u[0] = hi_pair(hq0.x, hq0.y); Ahl.u[1] = hi_pair(hq0.z, hq0.w);
        Ahl.u[2] = hi_pair(hq1.x, hq1.y); Ahl.u[3] = hi_pair(hq1.z, hq1.w);
        f32x4 aw = {0.f, 0.f, 0.f, 0.f};
        aw = __builtin_amdgcn_mfma_f32_16x16x32_bf16(Ahh.s, Bwh, aw, 0, 0, 0);
        aw = __builtin_amdgcn_mfma_f32_16x16x32_bf16(Ahl.s, Bwh, aw, 0, 0, 0);
        aw = __builtin_amdgcn_mfma_f32_16x16x32_bf16(Ahh.s, Bwl, aw, 0, 0, 0);
        if (u0 == 0 && lowq) {
            #pragma unroll
            for (int r = 0; r < 4; ++r)
                out_lds[(q * 4 + r) * TS + 49] = aw[r] + bout;
        }
    }

    __syncthreads();
    // ---- coalesced flush: 400 contiguous floats ----
    {
        float4* od = (float4*)(out + b0 * 50);
        const float4* os = (const float4*)out_lds;
        for (int i = lane; i < 100; i += 64) od[i] = os[i];
    }
}

extern "C" void kernel_launch(void* const* d_in, const int* in_sizes, int n_in,
                              void* d_out, int out_size, void* d_ws, size_t ws_size,
                              hipStream_t stream) {
    const float* x     = (const float*)d_in[0];
    const float* W_ih  = (const float*)d_in[1];
    const float* W_hh  = (const float*)d_in[2];
    const float* b_ih  = (const float*)d_in[3];
    const float* b_hh  = (const float*)d_in[4];
    const float* W_out = (const float*)d_in[5];
    const float* b_out = (const float*)d_in[6];
    const float* h0    = (const float*)d_in[7];
    const float* c0    = (const float*)d_in[8];
    float* out = (float*)d_out;

    dim3 grid(32768 / 8), block(64);
    lsnn_kernel<<<grid, block, 0, stream>>>(x, W_ih, W_hh, b_ih, b_hh,
                                            W_out, b_out, h0, c0, out);
}

// Round 7
// 170.709 us; speedup vs baseline: 3.2276x; 1.2898x over previous
//
#include <hip/hip_runtime.h>

// LSTM B=32768, T=50, I=2, H=32. 2048 blocks x 64 threads (1 wave / 16 rows).
// Full M=16 MFMA tiles, single-wave block: no barriers, no bpermute.
// Lane (u0,q) owns rows q*4+r (r=0..3) x units {u0, 16+u0} -> 8 complete
// (i,f,g,o) sets per lane in accumulators; activations fully in-register.
// Recurrent GEMM: mfma_f32_16x16x32_bf16 split precision (hh*Wh+hl*Wh+hh*Wl).
// h round-trips LDS packed (lo16|hi16) u32; same-wave RAW -> lgkmcnt only.
// x-projection: exact fp32 C-operand init, cw constants in VGPRs.
// Scales folded (-log2e / +2log2e); per set 5 exp2 + 2 rcp; only c clamped
// (gate z provably < 127/scale). Output head = 3 MFMAs vs replicated W_out.

#define TS 50
#define HSTR 36     // u32 stride of hpk rows (144 B): 16B-aligned
#define CL 30.0f    // exp2 arg clamp for tanh(c) only

typedef short short8 __attribute__((ext_vector_type(8)));
typedef float f32x4 __attribute__((ext_vector_type(4)));

__device__ __forceinline__ float fast_exp2(float x) {
    return __builtin_amdgcn_exp2f(x);
}
__device__ __forceinline__ float fast_rcp(float x) {
    return __builtin_amdgcn_rcpf(x);
}
// v ~= hi + lo (bf16 each, trunc). returns (lo<<16)|hi
__device__ __forceinline__ unsigned split_pack(float v) {
    unsigned u   = __float_as_uint(v);
    float    res = v - __uint_as_float(u & 0xffff0000u);
    return __builtin_amdgcn_perm(__float_as_uint(res), u, 0x07060302u);
}
// (a & 0xffff) | (b << 16)
__device__ __forceinline__ unsigned lo_pair(unsigned a, unsigned b) {
    return __builtin_amdgcn_perm(b, a, 0x05040100u);
}
// (a >> 16) | (b & 0xffff0000)
__device__ __forceinline__ unsigned hi_pair(unsigned a, unsigned b) {
    return __builtin_amdgcn_perm(b, a, 0x07060302u);
}

union U4S8 { uint4 v; short8 s; unsigned u[4]; };

__global__ __launch_bounds__(64, 2)
void lsnn_kernel(const float* __restrict__ x,
                 const float* __restrict__ W_ih,
                 const float* __restrict__ W_hh,
                 const float* __restrict__ b_ih,
                 const float* __restrict__ b_hh,
                 const float* __restrict__ W_out,
                 const float* __restrict__ b_out,
                 const float* __restrict__ h0,
                 const float* __restrict__ c0,
                 float* __restrict__ out)
{
    __shared__ __align__(16) float    x_lds[16 * 100];   // 6400 B
    __shared__ __align__(16) unsigned hpk[16 * HSTR];    // 2304 B
    __shared__ __align__(16) float    out_lds[16 * TS];  // 3200 B

    const int  lane = threadIdx.x;
    const int  u0   = lane & 15;
    const int  q    = lane >> 4;
    const long b0   = (long)blockIdx.x * 16;

    // ---- stage x: 1600 contiguous floats ----
    {
        const float4* xs = (const float4*)(x + b0 * 100);
        float4* xd = (float4*)x_lds;
        for (int i = lane; i < 400; i += 64) xd[i] = xs[i];
    }
    // ---- init packed h0 ----
    for (int i = lane; i < 512; i += 64) {
        int r = i >> 5, u = i & 31;
        hpk[r * HSTR + u] = split_pack(h0[b0 * 32 + i]);
    }

    const float L2E = 1.4426950408889634f;
    const float SG  = 2.0f * L2E;

    // ---- W_hh B-tiles (8): tile n -> gate n>>1, unit-half n&1, col u0 ----
    short8 Bh[8], Bl[8];
    float  wx0[8], wx1[8], bias[8];
    #pragma unroll
    for (int n = 0; n < 8; ++n) {
        const float s = ((n >> 1) == 2) ? (2.0f * L2E) : -L2E;
        const int   g = n * 16 + u0;
        const float* wr = W_hh + g * 32 + q * 8;
        U4S8 uh, ul;
        #pragma unroll
        for (int p = 0; p < 4; ++p) {
            unsigned p0 = split_pack(wr[2*p]   * s);
            unsigned p1 = split_pack(wr[2*p+1] * s);
            uh.u[p] = lo_pair(p0, p1);
            ul.u[p] = hi_pair(p0, p1);
        }
        Bh[n] = uh.s;  Bl[n] = ul.s;
        wx0[n]  = W_ih[g * 2 + 0] * s;
        wx1[n]  = W_ih[g * 2 + 1] * s;
        bias[n] = (b_ih[g] + b_hh[g]) * s;
    }
    // ---- head B-frag: B[k][n] = w_out[k] replicated over n ----
    short8 Bwh, Bwl;
    {
        U4S8 uh, ul;
        #pragma unroll
        for (int p = 0; p < 4; ++p) {
            unsigned p0 = split_pack(W_out[q * 8 + 2*p]);
            unsigned p1 = split_pack(W_out[q * 8 + 2*p + 1]);
            uh.u[p] = lo_pair(p0, p1);
            ul.u[p] = hi_pair(p0, p1);
        }
        Bwh = uh.s;  Bwl = ul.s;
    }
    const float bout = b_out[0];

    // ---- c-state: set (hu,r) -> row q*4+r, unit hu*16+u0 ----
    float cst[8];
    #pragma unroll
    for (int hu = 0; hu < 2; ++hu)
        #pragma unroll
        for (int r = 0; r < 4; ++r)
            cst[hu * 4 + r] = c0[(b0 + q * 4 + r) * 32 + hu * 16 + u0];

    const f32x4 ZV = {0.f, 0.f, 0.f, 0.f};
    const int abase = u0 * HSTR + q * 8;

    __syncthreads();

    #pragma unroll 1
    for (int t = 0; t < TS; ++t) {
        // ---- A-fragment h_t: row u0, k = q*8..q*8+7 ----
        uint4 hq0 = *(const uint4*)&hpk[abase];
        uint4 hq1 = *(const uint4*)&hpk[abase + 4];
        U4S8 Ahh, Ahl;
        Ahh.u[0] = lo_pair(hq0.x, hq0.y); Ahh.u[1] = lo_pair(hq0.z, hq0.w);
        Ahh.u[2] = lo_pair(hq1.x, hq1.y); Ahh.u[3] = lo_pair(hq1.z, hq1.w);
        Ahl.u[0] = hi_pair(hq0.x, hq0.y); Ahl.u[1] = hi_pair(hq0.z, hq0.w);
        Ahl.u[2] = hi_pair(hq1.x, hq1.y); Ahl.u[3] = hi_pair(hq1.z, hq1.w);

        // ---- output head for h_t (skip t=0: h0 not an output) ----
        if (t > 0) {
            f32x4 aw = ZV;
            aw = __builtin_amdgcn_mfma_f32_16x16x32_bf16(Ahh.s, Bwh, aw, 0, 0, 0);
            aw = __builtin_amdgcn_mfma_f32_16x16x32_bf16(Ahl.s, Bwh, aw, 0, 0, 0);
            aw = __builtin_amdgcn_mfma_f32_16x16x32_bf16(Ahh.s, Bwl, aw, 0, 0, 0);
            if (u0 == 0) {
                #pragma unroll
                for (int r = 0; r < 4; ++r)
                    out_lds[(q * 4 + r) * TS + (t - 1)] = aw[r] + bout;
            }
        }

        // ---- x values for C-init: rows q*4+r ----
        float xr0[4], xr1[4];
        #pragma unroll
        for (int r = 0; r < 4; ++r) {
            float2 xv = *(const float2*)&x_lds[(q * 4 + r) * 100 + 2 * t];
            xr0[r] = xv.x;  xr1[r] = xv.y;
        }

        // ---- gates: exact fp32 C-init + 3 split-h MFMAs per tile ----
        f32x4 acc[8];
        #pragma unroll
        for (int n = 0; n < 8; ++n) {
            f32x4 ci;
            #pragma unroll
            for (int r = 0; r < 4; ++r)
                ci[r] = fmaf(wx1[n], xr1[r], fmaf(wx0[n], xr0[r], bias[n]));
            acc[n] = __builtin_amdgcn_mfma_f32_16x16x32_bf16(Ahh.s, Bh[n], ci,     0, 0, 0);
            acc[n] = __builtin_amdgcn_mfma_f32_16x16x32_bf16(Ahl.s, Bh[n], acc[n], 0, 0, 0);
            acc[n] = __builtin_amdgcn_mfma_f32_16x16x32_bf16(Ahh.s, Bl[n], acc[n], 0, 0, 0);
        }

        // ---- activations: 8 in-register sets (hu, r); 5 exp2 + 2 rcp each ----
        #pragma unroll
        for (int hu = 0; hu < 2; ++hu) {
            #pragma unroll
            for (int r = 0; r < 4; ++r) {
                float zi = acc[0 + hu][r];    // i  (scaled -log2e)
                float zf = acc[2 + hu][r];    // f  (scaled -log2e)
                float zg = acc[4 + hu][r];    // g  (scaled +2log2e)
                float zo = acc[6 + hu][r];    // o  (scaled -log2e)
                float Av = fast_exp2(zi);
                float Bv = fast_exp2(zg);
                float Ev = fast_exp2(zf);
                float Ap = 1.0f + Av, Bp = 1.0f + Bv, Ep = 1.0f + Ev;
                float P1 = Ap * Bp;
                float R  = fast_rcp(P1 * Ep);
                float ig = (Bv - 1.0f) * (Ep * R);   // sigmoid(i)*tanh(g)
                float fv = P1 * R;                   // sigmoid(f)
                float c  = fmaf(fv, cst[hu * 4 + r], ig);
                cst[hu * 4 + r] = c;
                float Cv = fast_exp2(zo);
                float Dv = fast_exp2(fminf(SG * c, CL));
                float R2 = fast_rcp((1.0f + Cv) * (1.0f + Dv));
                float h  = (Dv - 1.0f) * R2;         // sigmoid(o)*tanh(c)
                hpk[(q * 4 + r) * HSTR + hu * 16 + u0] = split_pack(h);
            }
        }
    }

    // ---- final head for h_50 ----
    {
        uint4 hq0 = *(const uint4*)&hpk[abase];
        uint4 hq1 = *(const uint4*)&hpk[abase + 4];
        U4S8 Ahh, Ahl;
        Ahh.u[0] = lo_pair(hq0.x, hq0.y); Ahh.u[1] = lo_pair(hq0.z, hq0.w);
        Ahh.u[2] = lo_pair(hq1.x, hq1.y); Ahh.u[3] = lo_pair(hq1.z, hq1.w);
        Ahl.u[0] = hi_pair(hq0.x, hq0.y); Ahl.u[1] = hi_pair(hq0.z, hq0.w);
        Ahl.u[2] = hi_pair(hq1.x, hq1.y); Ahl.u[3] = hi_pair(hq1.z, hq1.w);
        f32x4 aw = {0.f, 0.f, 0.f, 0.f};
        aw = __builtin_amdgcn_mfma_f32_16x16x32_bf16(Ahh.s, Bwh, aw, 0, 0, 0);
        aw = __builtin_amdgcn_mfma_f32_16x16x32_bf16(Ahl.s, Bwh, aw, 0, 0, 0);
        aw = __builtin_amdgcn_mfma_f32_16x16x32_bf16(Ahh.s, Bwl, aw, 0, 0, 0);
        if (u0 == 0) {
            #pragma unroll
            for (int r = 0; r < 4; ++r)
                out_lds[(q * 4 + r) * TS + 49] = aw[r] + bout;
        }
    }

    __syncthreads();
    // ---- coalesced flush: 800 contiguous floats ----
    {
        float4* od = (float4*)(out + b0 * 50);
        const float4* os = (const float4*)out_lds;
        for (int i = lane; i < 200; i += 64) od[i] = os[i];
    }
}

extern "C" void kernel_launch(void* const* d_in, const int* in_sizes, int n_in,
                              void* d_out, int out_size, void* d_ws, size_t ws_size,
                              hipStream_t stream) {
    const float* x     = (const float*)d_in[0];
    const float* W_ih  = (const float*)d_in[1];
    const float* W_hh  = (const float*)d_in[2];
    const float* b_ih  = (const float*)d_in[3];
    const float* b_hh  = (const float*)d_in[4];
    const float* W_out = (const float*)d_in[5];
    const float* b_out = (const float*)d_in[6];
    const float* h0    = (const float*)d_in[7];
    const float* c0    = (const float*)d_in[8];
    float* out = (float*)d_out;

    dim3 grid(32768 / 16), block(64);
    lsnn_kernel<<<grid, block, 0, stream>>>(x, W_ih, W_hh, b_ih, b_hh,
                                            W_out, b_out, h0, c0, out);
}

// Round 8
// 166.808 us; speedup vs baseline: 3.3031x; 1.0234x over previous
//
#include <hip/hip_runtime.h>

// LSTM B=32768, T=50, I=2, H=32. 2048 blocks x 64 threads (1 wave / 16 rows).
// R7 structure (passed, 107us counter) + three changes:
//  1. De-phase: odd blocks s_sleep(20) (~1280cyc ~ half a t-iter) so the two
//     co-resident waves' trans bursts overlap each other's DS-wait windows
//     (R7: 42% idle, both waves phase-aligned).
//  2. Pair-batched reciprocals: 16 rcp -> 8 rcp per wave-t. Clamps: zg and c
//     at CL=14 only (sigmoid z's bounded ~9.5; pair products <= 2^66, safe).
//  3. x reads for t+1 issued before activations (never queue behind h writes).
// Core: full M=16 mfma_f32_16x16x32_bf16, split precision h (hh*Wh+hl*Wh+hh*Wl),
// h packed (lo16|hi16) u32 in LDS, no barriers in recurrence, head = 3 MFMAs.

#define TS 50
#define HSTR 36     // u32 stride of hpk rows (144 B): 16B-aligned
#define CL 14.0f    // exp2 arg clamp (zg, c): pair products <= 2^66

typedef short short8 __attribute__((ext_vector_type(8)));
typedef float f32x4 __attribute__((ext_vector_type(4)));

__device__ __forceinline__ float fast_exp2(float x) {
    return __builtin_amdgcn_exp2f(x);
}
__device__ __forceinline__ float fast_rcp(float x) {
    return __builtin_amdgcn_rcpf(x);
}
// v ~= hi + lo (bf16 each, trunc). returns (lo<<16)|hi
__device__ __forceinline__ unsigned split_pack(float v) {
    unsigned u   = __float_as_uint(v);
    float    res = v - __uint_as_float(u & 0xffff0000u);
    return __builtin_amdgcn_perm(__float_as_uint(res), u, 0x07060302u);
}
// (a & 0xffff) | (b << 16)
__device__ __forceinline__ unsigned lo_pair(unsigned a, unsigned b) {
    return __builtin_amdgcn_perm(b, a, 0x05040100u);
}
// (a >> 16) | (b & 0xffff0000)
__device__ __forceinline__ unsigned hi_pair(unsigned a, unsigned b) {
    return __builtin_amdgcn_perm(b, a, 0x07060302u);
}

union U4S8 { uint4 v; short8 s; unsigned u[4]; };

__global__ __launch_bounds__(64, 2)
void lsnn_kernel(const float* __restrict__ x,
                 const float* __restrict__ W_ih,
                 const float* __restrict__ W_hh,
                 const float* __restrict__ b_ih,
                 const float* __restrict__ b_hh,
                 const float* __restrict__ W_out,
                 const float* __restrict__ b_out,
                 const float* __restrict__ h0,
                 const float* __restrict__ c0,
                 float* __restrict__ out)
{
    __shared__ __align__(16) float    x_lds[16 * 100];   // 6400 B
    __shared__ __align__(16) unsigned hpk[16 * HSTR];    // 2304 B
    __shared__ __align__(16) float    out_lds[16 * TS];  // 3200 B

    const int  lane = threadIdx.x;
    const int  u0   = lane & 15;
    const int  q    = lane >> 4;
    const long b0   = (long)blockIdx.x * 16;

    // ---- stage x: 1600 contiguous floats ----
    {
        const float4* xs = (const float4*)(x + b0 * 100);
        float4* xd = (float4*)x_lds;
        for (int i = lane; i < 400; i += 64) xd[i] = xs[i];
    }
    // ---- init packed h0 ----
    for (int i = lane; i < 512; i += 64) {
        int r = i >> 5, u = i & 31;
        hpk[r * HSTR + u] = split_pack(h0[b0 * 32 + i]);
    }

    const float L2E = 1.4426950408889634f;
    const float SG  = 2.0f * L2E;

    // ---- W_hh B-tiles (8): tile n -> gate n>>1, unit-half n&1, col u0 ----
    short8 Bh[8], Bl[8];
    float  wx0[8], wx1[8], bias[8];
    #pragma unroll
    for (int n = 0; n < 8; ++n) {
        const float s = ((n >> 1) == 2) ? (2.0f * L2E) : -L2E;
        const int   g = n * 16 + u0;
        const float* wr = W_hh + g * 32 + q * 8;
        U4S8 uh, ul;
        #pragma unroll
        for (int p = 0; p < 4; ++p) {
            unsigned p0 = split_pack(wr[2*p]   * s);
            unsigned p1 = split_pack(wr[2*p+1] * s);
            uh.u[p] = lo_pair(p0, p1);
            ul.u[p] = hi_pair(p0, p1);
        }
        Bh[n] = uh.s;  Bl[n] = ul.s;
        wx0[n]  = W_ih[g * 2 + 0] * s;
        wx1[n]  = W_ih[g * 2 + 1] * s;
        bias[n] = (b_ih[g] + b_hh[g]) * s;
    }
    // ---- head B-frag: B[k][n] = w_out[k] replicated over n ----
    short8 Bwh, Bwl;
    {
        U4S8 uh, ul;
        #pragma unroll
        for (int p = 0; p < 4; ++p) {
            unsigned p0 = split_pack(W_out[q * 8 + 2*p]);
            unsigned p1 = split_pack(W_out[q * 8 + 2*p + 1]);
            uh.u[p] = lo_pair(p0, p1);
            ul.u[p] = hi_pair(p0, p1);
        }
        Bwh = uh.s;  Bwl = ul.s;
    }
    const float bout = b_out[0];

    // ---- c-state: set s = hu*4+r -> row q*4+r, unit hu*16+u0 ----
    float cst[8];
    #pragma unroll
    for (int hu = 0; hu < 2; ++hu)
        #pragma unroll
        for (int r = 0; r < 4; ++r)
            cst[hu * 4 + r] = c0[(b0 + q * 4 + r) * 32 + hu * 16 + u0];

    const f32x4 ZV = {0.f, 0.f, 0.f, 0.f};
    const int abase = u0 * HSTR + q * 8;

    __syncthreads();

    // ---- de-phase the two co-resident waves by ~half a t-iteration ----
    if (blockIdx.x & 1) __builtin_amdgcn_s_sleep(20);

    // ---- x prefetch for t=0 ----
    float2 xv[4];
    #pragma unroll
    for (int r = 0; r < 4; ++r)
        xv[r] = *(const float2*)&x_lds[(q * 4 + r) * 100];

    #pragma unroll 1
    for (int t = 0; t < TS; ++t) {
        // ---- A-fragment h_t: row u0, k = q*8..q*8+7 ----
        uint4 hq0 = *(const uint4*)&hpk[abase];
        uint4 hq1 = *(const uint4*)&hpk[abase + 4];
        U4S8 Ahh, Ahl;
        Ahh.u[0] = lo_pair(hq0.x, hq0.y); Ahh.u[1] = lo_pair(hq0.z, hq0.w);
        Ahh.u[2] = lo_pair(hq1.x, hq1.y); Ahh.u[3] = lo_pair(hq1.z, hq1.w);
        Ahl.u[0] = hi_pair(hq0.x, hq0.y); Ahl.u[1] = hi_pair(hq0.z, hq0.w);
        Ahl.u[2] = hi_pair(hq1.x, hq1.y); Ahl.u[3] = hi_pair(hq1.z, hq1.w);

        // ---- output head for h_t (skip t=0: h0 not an output) ----
        if (t > 0) {
            f32x4 aw = ZV;
            aw = __builtin_amdgcn_mfma_f32_16x16x32_bf16(Ahh.s, Bwh, aw, 0, 0, 0);
            aw = __builtin_amdgcn_mfma_f32_16x16x32_bf16(Ahl.s, Bwh, aw, 0, 0, 0);
            aw = __builtin_amdgcn_mfma_f32_16x16x32_bf16(Ahh.s, Bwl, aw, 0, 0, 0);
            if (u0 == 0) {
                #pragma unroll
                for (int r = 0; r < 4; ++r)
                    out_lds[(q * 4 + r) * TS + (t - 1)] = aw[r] + bout;
            }
        }

        // ---- gates: exact fp32 C-init + 3 split-h MFMAs per tile ----
        f32x4 acc[8];
        #pragma unroll
        for (int n = 0; n < 8; ++n) {
            f32x4 ci;
            #pragma unroll
            for (int r = 0; r < 4; ++r)
                ci[r] = fmaf(wx1[n], xv[r].y, fmaf(wx0[n], xv[r].x, bias[n]));
            acc[n] = __builtin_amdgcn_mfma_f32_16x16x32_bf16(Ahh.s, Bh[n], ci,     0, 0, 0);
            acc[n] = __builtin_amdgcn_mfma_f32_16x16x32_bf16(Ahl.s, Bh[n], acc[n], 0, 0, 0);
            acc[n] = __builtin_amdgcn_mfma_f32_16x16x32_bf16(Ahh.s, Bl[n], acc[n], 0, 0, 0);
        }

        // ---- prefetch x for t+1 (issues before activations / h writes) ----
        if (t + 1 < TS) {
            #pragma unroll
            for (int r = 0; r < 4; ++r)
                xv[r] = *(const float2*)&x_lds[(q * 4 + r) * 100 + 2 * (t + 1)];
        }

        // ---- activations: 8 sets s=hu*4+r, pair-batched rcp (pairs s, s+4) ----
        float Bvs[8], Evs[8], Cvs[8], abps[8], epvs[8], pps[8];
        #pragma unroll
        for (int s = 0; s < 8; ++s) {
            const int hu = s >> 2, r = s & 3;
            float zi = acc[0 + hu][r];                // i (scaled -log2e)
            float zf = acc[2 + hu][r];                // f (scaled -log2e)
            float zg = fminf(acc[4 + hu][r], CL);     // g (scaled +2log2e)
            float zo = acc[6 + hu][r];                // o (scaled -log2e)
            float Av = fast_exp2(zi);
            Bvs[s]   = fast_exp2(zg);
            Evs[s]   = fast_exp2(zf);
            Cvs[s]   = fast_exp2(zo);
            float Ap = 1.0f + Av, Bp = 1.0f + Bvs[s];
            epvs[s]  = 1.0f + Evs[s];
            abps[s]  = Ap * Bp;
            pps[s]   = abps[s] * epvs[s];
        }
        float rgs[8];
        #pragma unroll
        for (int s = 0; s < 4; ++s) {
            float pr = pps[s] * pps[s + 4];
            float ri = fast_rcp(pr);
            rgs[s]     = pps[s + 4] * ri;
            rgs[s + 4] = pps[s]     * ri;
        }
        float Dvs[8], qvs[8];
        #pragma unroll
        for (int s = 0; s < 8; ++s) {
            float fv = abps[s] * rgs[s];                       // sigmoid(f)
            float ig = (Bvs[s] - 1.0f) * (epvs[s] * rgs[s]);   // sig(i)*tanh(g)
            float c  = fmaf(fv, cst[s], ig);
            cst[s] = c;
            Dvs[s] = fast_exp2(fminf(SG * c, CL));             // e^{2c}
            qvs[s] = (1.0f + Cvs[s]) * (1.0f + Dvs[s]);
        }
        float rqs[8];
        #pragma unroll
        for (int s = 0; s < 4; ++s) {
            float qr = qvs[s] * qvs[s + 4];
            float ri = fast_rcp(qr);
            rqs[s]     = qvs[s + 4] * ri;
            rqs[s + 4] = qvs[s]     * ri;
        }
        #pragma unroll
        for (int s = 0; s < 8; ++s) {
            const int hu = s >> 2, r = s & 3;
            float h = (Dvs[s] - 1.0f) * rqs[s];                // sig(o)*tanh(c)
            hpk[(q * 4 + r) * HSTR + hu * 16 + u0] = split_pack(h);
        }
    }

    // ---- final head for h_50 ----
    {
        uint4 hq0 = *(const uint4*)&hpk[abase];
        uint4 hq1 = *(const uint4*)&hpk[abase + 4];
        U4S8 Ahh, Ahl;
        Ahh.u[0] = lo_pair(hq0.x, hq0.y); Ahh.u[1] = lo_pair(hq0.z, hq0.w);
        Ahh.u[2] = lo_pair(hq1.x, hq1.y); Ahh.u[3] = lo_pair(hq1.z, hq1.w);
        Ahl.u[0] = hi_pair(hq0.x, hq0.y); Ahl.u[1] = hi_pair(hq0.z, hq0.w);
        Ahl.u[2] = hi_pair(hq1.x, hq1.y); Ahl.u[3] = hi_pair(hq1.z, hq1.w);
        f32x4 aw = {0.f, 0.f, 0.f, 0.f};
        aw = __builtin_amdgcn_mfma_f32_16x16x32_bf16(Ahh.s, Bwh, aw, 0, 0, 0);
        aw = __builtin_amdgcn_mfma_f32_16x16x32_bf16(Ahl.s, Bwh, aw, 0, 0, 0);
        aw = __builtin_amdgcn_mfma_f32_16x16x32_bf16(Ahh.s, Bwl, aw, 0, 0, 0);
        if (u0 == 0) {
            #pragma unroll
            for (int r = 0; r < 4; ++r)
                out_lds[(q * 4 + r) * TS + 49] = aw[r] + bout;
        }
    }

    __syncthreads();
    // ---- coalesced flush: 800 contiguous floats ----
    {
        float4* od = (float4*)(out + b0 * 50);
        const float4* os = (const float4*)out_lds;
        for (int i = lane; i < 200; i += 64) od[i] = os[i];
    }
}

extern "C" void kernel_launch(void* const* d_in, const int* in_sizes, int n_in,
                              void* d_out, int out_size, void* d_ws, size_t ws_size,
                              hipStream_t stream) {
    const float* x     = (const float*)d_in[0];
    const float* W_ih  = (const float*)d_in[1];
    const float* W_hh  = (const float*)d_in[2];
    const float* b_ih  = (const float*)d_in[3];
    const float* b_hh  = (const float*)d_in[4];
    const float* W_out = (const float*)d_in[5];
    const float* b_out = (const float*)d_in[6];
    const float* h0    = (const float*)d_in[7];
    const float* c0    = (const float*)d_in[8];
    float* out = (float*)d_out;

    dim3 grid(32768 / 16), block(64);
    lsnn_kernel<<<grid, block, 0, stream>>>(x, W_ih, W_hh, b_ih, b_hh,
                                            W_out, b_out, h0, c0, out);
}

// Round 9
// 164.140 us; speedup vs baseline: 3.3568x; 1.0163x over previous
//
#include <hip/hip_runtime.h>

// LSTM B=32768, T=50, I=2, H=32. 512 blocks x 256 threads = 4 waves/block,
// each wave INDEPENDENT: own 16 batch rows, own private LDS region, NO
// __syncthreads anywhere (barrier-free recurrence). R8's wave-program
// unchanged otherwise. Rationale: single-wave blocks under-packed CUs
// (Occupancy 17.8% ~ 1.4 waves/SIMD; R2 18% vs R3 32% shows small blocks
// don't pack). 2 blocks/CU x 4 waves = 2 waves/SIMD sustained.
// Core: full M=16 mfma_f32_16x16x32_bf16, split precision h (hh*Wh+hl*Wh+hh*Wl),
// h packed (lo16|hi16) u32 in private LDS, head = 3 MFMAs vs replicated W_out,
// scales folded (-log2e/+2log2e), pair-batched rcp, clamps on zg and c only.

#define TS 50
#define HSTR 36     // u32 stride of hpk rows (144 B): 16B-aligned
#define CL 14.0f    // exp2 arg clamp (zg, c): pair products <= 2^66
#define WPB 4       // waves per block

typedef short short8 __attribute__((ext_vector_type(8)));
typedef float f32x4 __attribute__((ext_vector_type(4)));

__device__ __forceinline__ float fast_exp2(float x) {
    return __builtin_amdgcn_exp2f(x);
}
__device__ __forceinline__ float fast_rcp(float x) {
    return __builtin_amdgcn_rcpf(x);
}
// v ~= hi + lo (bf16 each, trunc). returns (lo<<16)|hi
__device__ __forceinline__ unsigned split_pack(float v) {
    unsigned u   = __float_as_uint(v);
    float    res = v - __uint_as_float(u & 0xffff0000u);
    return __builtin_amdgcn_perm(__float_as_uint(res), u, 0x07060302u);
}
// (a & 0xffff) | (b << 16)
__device__ __forceinline__ unsigned lo_pair(unsigned a, unsigned b) {
    return __builtin_amdgcn_perm(b, a, 0x05040100u);
}
// (a >> 16) | (b & 0xffff0000)
__device__ __forceinline__ unsigned hi_pair(unsigned a, unsigned b) {
    return __builtin_amdgcn_perm(b, a, 0x07060302u);
}

union U4S8 { uint4 v; short8 s; unsigned u[4]; };

__global__ __launch_bounds__(256, 2)
void lsnn_kernel(const float* __restrict__ x,
                 const float* __restrict__ W_ih,
                 const float* __restrict__ W_hh,
                 const float* __restrict__ b_ih,
                 const float* __restrict__ b_hh,
                 const float* __restrict__ W_out,
                 const float* __restrict__ b_out,
                 const float* __restrict__ h0,
                 const float* __restrict__ c0,
                 float* __restrict__ out)
{
    // Per-wave private regions: wave g uses index [g]. No cross-wave sharing.
    __shared__ __align__(16) float    x_lds[WPB][16 * 100];   // 25600 B
    __shared__ __align__(16) unsigned hpk[WPB][16 * HSTR];    //  9216 B
    __shared__ __align__(16) float    out_lds[WPB][16 * TS];  // 12800 B

    const int  g_w  = threadIdx.x >> 6;   // wave id in block
    const int  lane = threadIdx.x & 63;
    const int  u0   = lane & 15;
    const int  q    = lane >> 4;
    const long b0   = ((long)blockIdx.x * WPB + g_w) * 16;

    float*    xw = x_lds[g_w];
    unsigned* hw = hpk[g_w];
    float*    ow = out_lds[g_w];

    // ---- stage this wave's x: 1600 contiguous floats ----
    {
        const float4* xs = (const float4*)(x + b0 * 100);
        float4* xd = (float4*)xw;
        for (int i = lane; i < 400; i += 64) xd[i] = xs[i];
    }
    // ---- init packed h0 (wave-private) ----
    for (int i = lane; i < 512; i += 64) {
        int r = i >> 5, u = i & 31;
        hw[r * HSTR + u] = split_pack(h0[b0 * 32 + i]);
    }

    const float L2E = 1.4426950408889634f;
    const float SG  = 2.0f * L2E;

    // ---- W_hh B-tiles (8): tile n -> gate n>>1, unit-half n&1, col u0 ----
    short8 Bh[8], Bl[8];
    float  wx0[8], wx1[8], bias[8];
    #pragma unroll
    for (int n = 0; n < 8; ++n) {
        const float s = ((n >> 1) == 2) ? (2.0f * L2E) : -L2E;
        const int   gg = n * 16 + u0;
        const float* wr = W_hh + gg * 32 + q * 8;
        U4S8 uh, ul;
        #pragma unroll
        for (int p = 0; p < 4; ++p) {
            unsigned p0 = split_pack(wr[2*p]   * s);
            unsigned p1 = split_pack(wr[2*p+1] * s);
            uh.u[p] = lo_pair(p0, p1);
            ul.u[p] = hi_pair(p0, p1);
        }
        Bh[n] = uh.s;  Bl[n] = ul.s;
        wx0[n]  = W_ih[gg * 2 + 0] * s;
        wx1[n]  = W_ih[gg * 2 + 1] * s;
        bias[n] = (b_ih[gg] + b_hh[gg]) * s;
    }
    // ---- head B-frag: B[k][n] = w_out[k] replicated over n ----
    short8 Bwh, Bwl;
    {
        U4S8 uh, ul;
        #pragma unroll
        for (int p = 0; p < 4; ++p) {
            unsigned p0 = split_pack(W_out[q * 8 + 2*p]);
            unsigned p1 = split_pack(W_out[q * 8 + 2*p + 1]);
            uh.u[p] = lo_pair(p0, p1);
            ul.u[p] = hi_pair(p0, p1);
        }
        Bwh = uh.s;  Bwl = ul.s;
    }
    const float bout = b_out[0];

    // ---- c-state: set s = hu*4+r -> row q*4+r, unit hu*16+u0 ----
    float cst[8];
    #pragma unroll
    for (int hu = 0; hu < 2; ++hu)
        #pragma unroll
        for (int r = 0; r < 4; ++r)
            cst[hu * 4 + r] = c0[(b0 + q * 4 + r) * 32 + hu * 16 + u0];

    const f32x4 ZV = {0.f, 0.f, 0.f, 0.f};
    const int abase = u0 * HSTR + q * 8;

    // ---- x prefetch for t=0 (wave-private data: no barrier needed) ----
    float2 xv[4];
    #pragma unroll
    for (int r = 0; r < 4; ++r)
        xv[r] = *(const float2*)&xw[(q * 4 + r) * 100];

    #pragma unroll 1
    for (int t = 0; t < TS; ++t) {
        // ---- A-fragment h_t: row u0, k = q*8..q*8+7 ----
        uint4 hq0 = *(const uint4*)&hw[abase];
        uint4 hq1 = *(const uint4*)&hw[abase + 4];
        U4S8 Ahh, Ahl;
        Ahh.u[0] = lo_pair(hq0.x, hq0.y); Ahh.u[1] = lo_pair(hq0.z, hq0.w);
        Ahh.u[2] = lo_pair(hq1.x, hq1.y); Ahh.u[3] = lo_pair(hq1.z, hq1.w);
        Ahl.u[0] = hi_pair(hq0.x, hq0.y); Ahl.u[1] = hi_pair(hq0.z, hq0.w);
        Ahl.u[2] = hi_pair(hq1.x, hq1.y); Ahl.u[3] = hi_pair(hq1.z, hq1.w);

        // ---- output head for h_t (skip t=0: h0 not an output) ----
        if (t > 0) {
            f32x4 aw = ZV;
            aw = __builtin_amdgcn_mfma_f32_16x16x32_bf16(Ahh.s, Bwh, aw, 0, 0, 0);
            aw = __builtin_amdgcn_mfma_f32_16x16x32_bf16(Ahl.s, Bwh, aw, 0, 0, 0);
            aw = __builtin_amdgcn_mfma_f32_16x16x32_bf16(Ahh.s, Bwl, aw, 0, 0, 0);
            if (u0 == 0) {
                #pragma unroll
                for (int r = 0; r < 4; ++r)
                    ow[(q * 4 + r) * TS + (t - 1)] = aw[r] + bout;
            }
        }

        // ---- gates: exact fp32 C-init + 3 split-h MFMAs per tile ----
        f32x4 acc[8];
        #pragma unroll
        for (int n = 0; n < 8; ++n) {
            f32x4 ci;
            #pragma unroll
            for (int r = 0; r < 4; ++r)
                ci[r] = fmaf(wx1[n], xv[r].y, fmaf(wx0[n], xv[r].x, bias[n]));
            acc[n] = __builtin_amdgcn_mfma_f32_16x16x32_bf16(Ahh.s, Bh[n], ci,     0, 0, 0);
            acc[n] = __builtin_amdgcn_mfma_f32_16x16x32_bf16(Ahl.s, Bh[n], acc[n], 0, 0, 0);
            acc[n] = __builtin_amdgcn_mfma_f32_16x16x32_bf16(Ahh.s, Bl[n], acc[n], 0, 0, 0);
        }

        // ---- prefetch x for t+1 ----
        if (t + 1 < TS) {
            #pragma unroll
            for (int r = 0; r < 4; ++r)
                xv[r] = *(const float2*)&xw[(q * 4 + r) * 100 + 2 * (t + 1)];
        }

        // ---- activations: 8 sets s=hu*4+r, pair-batched rcp (pairs s, s+4) ----
        float Bvs[8], Cvs[8], abps[8], epvs[8], pps[8];
        #pragma unroll
        for (int s = 0; s < 8; ++s) {
            const int hu = s >> 2, r = s & 3;
            float zi = acc[0 + hu][r];                // i (scaled -log2e)
            float zf = acc[2 + hu][r];                // f (scaled -log2e)
            float zg = fminf(acc[4 + hu][r], CL);     // g (scaled +2log2e)
            float zo = acc[6 + hu][r];                // o (scaled -log2e)
            float Av = fast_exp2(zi);
            Bvs[s]   = fast_exp2(zg);
            float Ev = fast_exp2(zf);
            Cvs[s]   = fast_exp2(zo);
            float Ap = 1.0f + Av, Bp = 1.0f + Bvs[s];
            epvs[s]  = 1.0f + Ev;
            abps[s]  = Ap * Bp;
            pps[s]   = abps[s] * epvs[s];
        }
        float rgs[8];
        #pragma unroll
        for (int s = 0; s < 4; ++s) {
            float pr = pps[s] * pps[s + 4];
            float ri = fast_rcp(pr);
            rgs[s]     = pps[s + 4] * ri;
            rgs[s + 4] = pps[s]     * ri;
        }
        float Dvs[8], qvs[8];
        #pragma unroll
        for (int s = 0; s < 8; ++s) {
            float fv = abps[s] * rgs[s];                       // sigmoid(f)
            float ig = (Bvs[s] - 1.0f) * (epvs[s] * rgs[s]);   // sig(i)*tanh(g)
            float c  = fmaf(fv, cst[s], ig);
            cst[s] = c;
            Dvs[s] = fast_exp2(fminf(SG * c, CL));             // e^{2c}
            qvs[s] = (1.0f + Cvs[s]) * (1.0f + Dvs[s]);
        }
        float rqs[8];
        #pragma unroll
        for (int s = 0; s < 4; ++s) {
            float qr = qvs[s] * qvs[s + 4];
            float ri = fast_rcp(qr);
            rqs[s]     = qvs[s + 4] * ri;
            rqs[s + 4] = qvs[s]     * ri;
        }
        #pragma unroll
        for (int s = 0; s < 8; ++s) {
            const int hu = s >> 2, r = s & 3;
            float h = (Dvs[s] - 1.0f) * rqs[s];                // sig(o)*tanh(c)
            hw[(q * 4 + r) * HSTR + hu * 16 + u0] = split_pack(h);
        }
    }

    // ---- final head for h_50 ----
    {
        uint4 hq0 = *(const uint4*)&hw[abase];
        uint4 hq1 = *(const uint4*)&hw[abase + 4];
        U4S8 Ahh, Ahl;
        Ahh.u[0] = lo_pair(hq0.x, hq0.y); Ahh.u[1] = lo_pair(hq0.z, hq0.w);
        Ahh.u[2] = lo_pair(hq1.x, hq1.y); Ahh.u[3] = lo_pair(hq1.z, hq1.w);
        Ahl.u[0] = hi_pair(hq0.x, hq0.y); Ahl.u[1] = hi_pair(hq0.z, hq0.w);
        Ahl.u[2] = hi_pair(hq1.x, hq1.y); Ahl.u[3] = hi_pair(hq1.z, hq1.w);
        f32x4 aw = {0.f, 0.f, 0.f, 0.f};
        aw = __builtin_amdgcn_mfma_f32_16x16x32_bf16(Ahh.s, Bwh, aw, 0, 0, 0);
        aw = __builtin_amdgcn_mfma_f32_16x16x32_bf16(Ahl.s, Bwh, aw, 0, 0, 0);
        aw = __builtin_amdgcn_mfma_f32_16x16x32_bf16(Ahh.s, Bwl, aw, 0, 0, 0);
        if (u0 == 0) {
            #pragma unroll
            for (int r = 0; r < 4; ++r)
                ow[(q * 4 + r) * TS + 49] = aw[r] + bout;
        }
    }

    // ---- coalesced flush of this wave's 800 contiguous floats (no barrier:
    //      each wave flushes only its own region) ----
    {
        float4* od = (float4*)(out + b0 * 50);
        const float4* os = (const float4*)ow;
        for (int i = lane; i < 200; i += 64) od[i] = os[i];
    }
}

extern "C" void kernel_launch(void* const* d_in, const int* in_sizes, int n_in,
                              void* d_out, int out_size, void* d_ws, size_t ws_size,
                              hipStream_t stream) {
    const float* x     = (const float*)d_in[0];
    const float* W_ih  = (const float*)d_in[1];
    const float* W_hh  = (const float*)d_in[2];
    const float* b_ih  = (const float*)d_in[3];
    const float* b_hh  = (const float*)d_in[4];
    const float* W_out = (const float*)d_in[5];
    const float* b_out = (const float*)d_in[6];
    const float* h0    = (const float*)d_in[7];
    const float* c0    = (const float*)d_in[8];
    float* out = (float*)d_out;

    dim3 grid(32768 / (16 * WPB)), block(64 * WPB);
    lsnn_kernel<<<grid, block, 0, stream>>>(x, W_ih, W_hh, b_ih, b_hh,
                                            W_out, b_out, h0, c0, out);
}